// Round 8
// baseline (332.227 us; speedup 1.0000x reference)
//
#include <hip/hip_runtime.h>
#include <hip/hip_bf16.h>
#include <math.h>

#define V 100000
#define H 256
#define B 512

typedef __bf16 bf16x8 __attribute__((ext_vector_type(8)));
typedef float  f32x4  __attribute__((ext_vector_type(4)));

__device__ __forceinline__ unsigned short f32_bf16_rne(float x) {
    unsigned u = __float_as_uint(x);
    u += 0x7FFFu + ((u >> 16) & 1u);            // round-to-nearest-even
    return (unsigned short)(u >> 16);
}
__device__ __forceinline__ float bf16u_f32(unsigned short h) {
    return __uint_as_float(((unsigned)h) << 16);
}
__device__ __forceinline__ float fast_tanh(float x) {
    // tanh(x) = 1 - 2/(exp2(2x*log2e)+1); saturates correctly (proven r6)
    float e = __builtin_exp2f(x * 2.8853900817779268f);
    return 1.f - 2.f * __builtin_amdgcn_rcpf(e + 1.f);
}

// ---------------------------------------------------------------------------
// Kernel 1 (v2): GRU cell, 8 batches per block (64 blocks). w_hh is read once
// per block (50 MB total vs 402 MB in the 1-batch/block version); the 24
// scattered w_ih gathers are issued before the w_hh loop so their latency
// hides under it. Math identical to the proven v1 path.
// ---------------------------------------------------------------------------
#define BPB 8

__global__ __launch_bounds__(256) void gru_cell_v2(
    const int*   __restrict__ input,
    const float* __restrict__ hidden,
    const float* __restrict__ w_ih,
    const float* __restrict__ w_hh,
    const float* __restrict__ b_ih,
    const float* __restrict__ b_hh,
    float*       __restrict__ h_out,
    unsigned short* __restrict__ h_hi_p,   // may be null (fallback path)
    unsigned short* __restrict__ h_lo_p)
{
    const int b0 = blockIdx.x * BPB;
    const int j  = threadIdx.x;   // hidden unit 0..255

    __shared__ float hs[BPB][H];   // 8 KB
    __shared__ int   idxs[BPB];
    #pragma unroll
    for (int bb = 0; bb < BPB; ++bb)
        hs[bb][j] = hidden[(b0 + bb) * H + j];
    if (j < BPB) idxs[j] = input[b0 + j];
    __syncthreads();

    // --- scattered gathers (issued early; latency hidden under w_hh loop) ---
    float gir[BPB], giz[BPB], gin[BPB];
    #pragma unroll
    for (int bb = 0; bb < BPB; ++bb) {
        const int idx = idxs[bb];
        gir[bb] = w_ih[(size_t) j          * V + idx];
        giz[bb] = w_ih[(size_t)(j +     H) * V + idx];
        gin[bb] = w_ih[(size_t)(j + 2 * H) * V + idx];
    }

    // --- gh: 3 dot-products vs 8 batches, w_hh rows in regs, h via LDS bcast ---
    const float4* wr = reinterpret_cast<const float4*>(&w_hh[ j          * H]);
    const float4* wz = reinterpret_cast<const float4*>(&w_hh[(j +     H) * H]);
    const float4* wn = reinterpret_cast<const float4*>(&w_hh[(j + 2 * H) * H]);

    float ar[BPB], az[BPB], an[BPB];
    #pragma unroll
    for (int bb = 0; bb < BPB; ++bb) { ar[bb] = 0.f; az[bb] = 0.f; an[bb] = 0.f; }

    #pragma unroll 4
    for (int k = 0; k < H / 4; ++k) {
        const float4 a = wr[k];
        const float4 c = wz[k];
        const float4 d = wn[k];
        #pragma unroll
        for (int bb = 0; bb < BPB; ++bb) {
            const float4 hv = *reinterpret_cast<const float4*>(&hs[bb][k * 4]);
            ar[bb] += a.x * hv.x + a.y * hv.y + a.z * hv.z + a.w * hv.w;
            az[bb] += c.x * hv.x + c.y * hv.y + c.z * hv.z + c.w * hv.w;
            an[bb] += d.x * hv.x + d.y * hv.y + d.z * hv.z + d.w * hv.w;
        }
    }

    const float bir = b_ih[j], biz = b_ih[j + H], bin = b_ih[j + 2 * H];
    const float bhr = b_hh[j], bhz = b_hh[j + H], bhn = b_hh[j + 2 * H];

    #pragma unroll
    for (int bb = 0; bb < BPB; ++bb) {
        const float r = 1.f / (1.f + expf(-(gir[bb] + bir + ar[bb] + bhr)));
        const float z = 1.f / (1.f + expf(-(giz[bb] + biz + az[bb] + bhz)));
        const float n = tanhf(gin[bb] + bin + r * (an[bb] + bhn));
        const float hprev = hs[bb][j];
        const float val = (1.f - z) * n + z * hprev;

        h_out[(b0 + bb) * H + j] = val;
        if (h_hi_p != nullptr) {
            const unsigned short hh = f32_bf16_rne(val);
            h_hi_p[(b0 + bb) * H + j] = hh;
            h_lo_p[(b0 + bb) * H + j] = f32_bf16_rne(val - bf16u_f32(hh));
        }
    }
}

// ---------------------------------------------------------------------------
// Kernel 2 (new schedule): logit = tanh(h_new @ w_out.T + b_out).
// 2-phase double-buffered split-bf16 MFMA:
//  - w fp32 loaded to regs one chunk ahead, hi/lo-split + ds_write into the
//    ALTERNATE LDS buffer while compute reads the current one -> ONE barrier
//    per chunk, stage latency hidden (fixes round-5's per-chunk vmcnt drain).
//  - h A-fragments come straight from the pre-split bf16 planes (L2-hot,
//    512 KB) into registers, prefetched one full chunk ahead (fixes round-7's
//    in-loop L2 latency). No h LDS at all.
// Tile 64b x 128v, BK=64, 4 waves (2x2). LDS 64 KB -> 2 blocks/CU.
// Fragment layout / swizzle / epilogue identical to the verified r4-r6 path.
// ---------------------------------------------------------------------------
#define BM  64
#define BN  128
#define BK  64
#define NVB 782   // ceil(V/BN)
#define NBB 8     // B/BM

__global__ __launch_bounds__(256, 2) void out_gemm_pipe(
    const float*          __restrict__ w_out,  // (V,H) fp32
    const unsigned short* __restrict__ hhi_g,  // (B,H) bf16 hi plane
    const unsigned short* __restrict__ hlo_g,  // (B,H) bf16 lo plane
    const float*          __restrict__ b_out,  // (V)
    float*                __restrict__ logit)  // (B,V)
{
    __shared__ unsigned short w_hi_s0[BN * BK];   // 16 KB each
    __shared__ unsigned short w_lo_s0[BN * BK];
    __shared__ unsigned short w_hi_s1[BN * BK];
    __shared__ unsigned short w_lo_s1[BN * BK];

    const int tid  = threadIdx.x;
    const int lane = tid & 63;
    const int wid  = tid >> 6;
    const int wm   = wid >> 1;      // batch half (0..1)
    const int wn   = wid & 1;       // vocab half (0..1)

    // XCD-chunked bijective swizzle, batch-fastest (proven: FETCH ~53 MB).
    const int bid = blockIdx.x;                    // 0..6255
    const int wg  = (bid & 7) * NVB + (bid >> 3);
    const int bx  = wg & 7;                        // batch block
    const int by  = wg >> 3;                       // vocab block
    const int b0  = bx * BM;
    const int v0  = by * BN;

    float4 wreg[8];

    auto load_w = [&](int k0) {
        #pragma unroll
        for (int i = 0; i < 8; ++i) {
            const int u   = i * 256 + tid;
            const int row = u >> 4;            // 0..127 local vocab row
            const int k4  = (u & 15) << 2;     // 0..60
            int vg = v0 + row; if (vg > V - 1) vg = V - 1;  // clamp; masked store
            wreg[i] = *reinterpret_cast<const float4*>(&w_out[(size_t)vg * H + k0 + k4]);
        }
    };

    auto store_w = [&](unsigned short* whi_b, unsigned short* wlo_b) {
        #pragma unroll
        for (int i = 0; i < 8; ++i) {
            const int u   = i * 256 + tid;
            const int row = u >> 4;
            const int k4  = (u & 15) << 2;
            const int off = row * (BK * 2) + ((k4 * 2) ^ ((row & 7) << 4));
            const float f[4] = {wreg[i].x, wreg[i].y, wreg[i].z, wreg[i].w};
            unsigned short hv[4], lv[4];
            #pragma unroll
            for (int jj = 0; jj < 4; ++jj) {
                hv[jj] = f32_bf16_rne(f[jj]);
                lv[jj] = f32_bf16_rne(f[jj] - bf16u_f32(hv[jj]));
            }
            *reinterpret_cast<ushort4*>(reinterpret_cast<char*>(whi_b) + off) =
                make_ushort4(hv[0], hv[1], hv[2], hv[3]);
            *reinterpret_cast<ushort4*>(reinterpret_cast<char*>(wlo_b) + off) =
                make_ushort4(lv[0], lv[1], lv[2], lv[3]);
        }
    };

    // A fragments: [i*2+ks], i = 16-row group, ks = k-half of the chunk.
    auto load_A = [&](bf16x8* ah, bf16x8* al, int t) {
        #pragma unroll
        for (int i = 0; i < 2; ++i) {
            #pragma unroll
            for (int ks = 0; ks < 2; ++ks) {
                const size_t ho = ((size_t)(b0 + wm * 32 + i * 16 + (lane & 15)) * H
                                   + t * BK + ks * 32 + (lane >> 4) * 8) * 2;
                ah[i * 2 + ks] = *reinterpret_cast<const bf16x8*>(
                                     reinterpret_cast<const char*>(hhi_g) + ho);
                al[i * 2 + ks] = *reinterpret_cast<const bf16x8*>(
                                     reinterpret_cast<const char*>(hlo_g) + ho);
            }
        }
    };

    f32x4 acc[2][4];
    #pragma unroll
    for (int i = 0; i < 2; ++i)
        #pragma unroll
        for (int n = 0; n < 4; ++n)
            acc[i][n] = f32x4{0.f, 0.f, 0.f, 0.f};

    auto compute = [&](const bf16x8* ah, const bf16x8* al,
                       const unsigned short* whi_b, const unsigned short* wlo_b) {
        #pragma unroll
        for (int ks = 0; ks < 2; ++ks) {
            const int kb = ks * 64 + (lane >> 4) * 16;   // LDS k byte offset
            bf16x8 bh[4], bl[4];
            #pragma unroll
            for (int n = 0; n < 4; ++n) {
                const int row = wn * 64 + n * 16 + (lane & 15);
                const int off = row * (BK * 2) + (kb ^ ((row & 7) << 4));
                bh[n] = *reinterpret_cast<const bf16x8*>(
                            reinterpret_cast<const char*>(whi_b) + off);
                bl[n] = *reinterpret_cast<const bf16x8*>(
                            reinterpret_cast<const char*>(wlo_b) + off);
            }
            #pragma unroll
            for (int n = 0; n < 4; ++n) {
                #pragma unroll
                for (int i = 0; i < 2; ++i) {
                    const bf16x8 a_h = ah[i * 2 + ks];
                    const bf16x8 a_l = al[i * 2 + ks];
                    acc[i][n] = __builtin_amdgcn_mfma_f32_16x16x32_bf16(a_h, bh[n], acc[i][n], 0, 0, 0);
                    acc[i][n] = __builtin_amdgcn_mfma_f32_16x16x32_bf16(a_h, bl[n], acc[i][n], 0, 0, 0);
                    acc[i][n] = __builtin_amdgcn_mfma_f32_16x16x32_bf16(a_l, bh[n], acc[i][n], 0, 0, 0);
                }
            }
        }
    };

    bf16x8 ahE[4], alE[4], ahO[4], alO[4];

    // Prologue: chunk 0 staged (full latency paid once).
    load_w(0);
    load_A(ahE, alE, 0);
    store_w(w_hi_s0, w_lo_s0);
    __syncthreads();

    #pragma unroll
    for (int t = 0; t < 4; ++t) {
        bf16x8* ahc = (t & 1) ? ahO : ahE;
        bf16x8* alc = (t & 1) ? alO : alE;
        bf16x8* ahn = (t & 1) ? ahE : ahO;
        bf16x8* aln = (t & 1) ? alE : alO;
        unsigned short* whc = (t & 1) ? w_hi_s1 : w_hi_s0;
        unsigned short* wlc = (t & 1) ? w_lo_s1 : w_lo_s0;
        unsigned short* whn = (t & 1) ? w_hi_s0 : w_hi_s1;
        unsigned short* wln = (t & 1) ? w_lo_s0 : w_lo_s1;

        if (t < 3) {                    // issue next chunk's global loads NOW
            load_w((t + 1) * BK);
            load_A(ahn, aln, t + 1);
        }
        compute(ahc, alc, whc, wlc);    // ds_read + 48 MFMA on current buffer
        if (t < 3)
            store_w(whn, wln);          // waits wregs, converts, writes OTHER buf
        __syncthreads();                // one barrier per chunk
    }

    // Epilogue: bias + tanh + masked store. C/D: col=lane&15, row=(lane>>4)*4+r.
    float bias[4];
    int   cols[4];
    #pragma unroll
    for (int n = 0; n < 4; ++n) {
        const int c = v0 + wn * 64 + n * 16 + (lane & 15);
        cols[n] = c;
        bias[n] = (c < V) ? b_out[c] : 0.f;
    }
    const int rbase = b0 + wm * 32 + (lane >> 4) * 4;
    #pragma unroll
    for (int i = 0; i < 2; ++i) {
        #pragma unroll
        for (int r = 0; r < 4; ++r) {
            const int row = rbase + i * 16 + r;
            float* dst = logit + (size_t)row * V;
            #pragma unroll
            for (int n = 0; n < 4; ++n) {
                if (cols[n] < V)
                    dst[cols[n]] = fast_tanh(acc[i][n][r] + bias[n]);
            }
        }
    }
}

// ---------------------------------------------------------------------------
// Fallback kernel (round-4, proven): reg-staged split-bf16 GEMM, used only if
// ws_size can't hold the h planes.
// ---------------------------------------------------------------------------
__global__ __launch_bounds__(256) void out_gemm_mfma_reg(
    const float* __restrict__ hnew,
    const float* __restrict__ w_out,
    const float* __restrict__ b_out,
    float*       __restrict__ logit)
{
    __shared__ unsigned short w_hi[BN * BK];
    __shared__ unsigned short w_lo[BN * BK];
    __shared__ unsigned short h_hi[BM * BK];
    __shared__ unsigned short h_lo[BM * BK];

    const int tid  = threadIdx.x;
    const int lane = tid & 63;
    const int wid  = tid >> 6;
    const int wm   = wid >> 1;
    const int wn   = wid & 1;

    const int bid = blockIdx.x;
    const int wg  = (bid & 7) * NVB + (bid >> 3);
    const int bx  = wg & 7;
    const int by  = wg >> 3;
    const int b0  = bx * BM;
    const int v0  = by * BN;

    float4 wreg[8];
    float4 hreg[4];

    auto load_chunk = [&](int k0) {
        #pragma unroll
        for (int i = 0; i < 8; ++i) {
            const int idx4 = i * 256 + tid;
            const int row  = idx4 >> 4;
            const int k4   = (idx4 & 15) << 2;
            int vg = v0 + row; if (vg > V - 1) vg = V - 1;
            wreg[i] = *reinterpret_cast<const float4*>(&w_out[(size_t)vg * H + k0 + k4]);
        }
        #pragma unroll
        for (int i = 0; i < 4; ++i) {
            const int idx4 = i * 256 + tid;
            const int row  = idx4 >> 4;
            const int k4   = (idx4 & 15) << 2;
            hreg[i] = *reinterpret_cast<const float4*>(&hnew[(b0 + row) * H + k0 + k4]);
        }
    };

    auto store_chunk = [&]() {
        #pragma unroll
        for (int i = 0; i < 8; ++i) {
            const int idx4 = i * 256 + tid;
            const int row  = idx4 >> 4;
            const int k4   = (idx4 & 15) << 2;
            const int off  = row * (BK * 2) + ((k4 * 2) ^ ((row & 7) << 4));
            const float f[4] = {wreg[i].x, wreg[i].y, wreg[i].z, wreg[i].w};
            unsigned short hv[4], lv[4];
            #pragma unroll
            for (int jj = 0; jj < 4; ++jj) {
                hv[jj] = f32_bf16_rne(f[jj]);
                lv[jj] = f32_bf16_rne(f[jj] - bf16u_f32(hv[jj]));
            }
            *reinterpret_cast<ushort4*>(reinterpret_cast<char*>(w_hi) + off) =
                make_ushort4(hv[0], hv[1], hv[2], hv[3]);
            *reinterpret_cast<ushort4*>(reinterpret_cast<char*>(w_lo) + off) =
                make_ushort4(lv[0], lv[1], lv[2], lv[3]);
        }
        #pragma unroll
        for (int i = 0; i < 4; ++i) {
            const int idx4 = i * 256 + tid;
            const int row  = idx4 >> 4;
            const int k4   = (idx4 & 15) << 2;
            const int off  = row * (BK * 2) + ((k4 * 2) ^ ((row & 7) << 4));
            const float f[4] = {hreg[i].x, hreg[i].y, hreg[i].z, hreg[i].w};
            unsigned short hv[4], lv[4];
            #pragma unroll
            for (int jj = 0; jj < 4; ++jj) {
                hv[jj] = f32_bf16_rne(f[jj]);
                lv[jj] = f32_bf16_rne(f[jj] - bf16u_f32(hv[jj]));
            }
            *reinterpret_cast<ushort4*>(reinterpret_cast<char*>(h_hi) + off) =
                make_ushort4(hv[0], hv[1], hv[2], hv[3]);
            *reinterpret_cast<ushort4*>(reinterpret_cast<char*>(h_lo) + off) =
                make_ushort4(lv[0], lv[1], lv[2], lv[3]);
        }
    };

    f32x4 acc[2][4];
    #pragma unroll
    for (int i = 0; i < 2; ++i)
        #pragma unroll
        for (int n = 0; n < 4; ++n)
            acc[i][n] = f32x4{0.f, 0.f, 0.f, 0.f};

    auto compute = [&]() {
        #pragma unroll
        for (int ks = 0; ks < 2; ++ks) {
            const int kb = ks * 64 + (lane >> 4) * 16;
            bf16x8 ah[2], al[2];
            #pragma unroll
            for (int i = 0; i < 2; ++i) {
                const int row = wm * 32 + i * 16 + (lane & 15);
                const int off = row * (BK * 2) + (kb ^ ((row & 7) << 4));
                ah[i] = *reinterpret_cast<const bf16x8*>(
                            reinterpret_cast<const char*>(h_hi) + off);
                al[i] = *reinterpret_cast<const bf16x8*>(
                            reinterpret_cast<const char*>(h_lo) + off);
            }
            #pragma unroll
            for (int n = 0; n < 4; ++n) {
                const int row = wn * 64 + n * 16 + (lane & 15);
                const int off = row * (BK * 2) + (kb ^ ((row & 7) << 4));
                const bf16x8 bh = *reinterpret_cast<const bf16x8*>(
                            reinterpret_cast<const char*>(w_hi) + off);
                const bf16x8 bl = *reinterpret_cast<const bf16x8*>(
                            reinterpret_cast<const char*>(w_lo) + off);
                #pragma unroll
                for (int i = 0; i < 2; ++i) {
                    acc[i][n] = __builtin_amdgcn_mfma_f32_16x16x32_bf16(ah[i], bh, acc[i][n], 0, 0, 0);
                    acc[i][n] = __builtin_amdgcn_mfma_f32_16x16x32_bf16(ah[i], bl, acc[i][n], 0, 0, 0);
                    acc[i][n] = __builtin_amdgcn_mfma_f32_16x16x32_bf16(al[i], bh, acc[i][n], 0, 0, 0);
                }
            }
        }
    };

    load_chunk(0);
    store_chunk();
    __syncthreads();
    for (int t = 0; t < 4; ++t) {
        if (t < 3) load_chunk((t + 1) * BK);
        compute();
        __syncthreads();
        if (t < 3) { store_chunk(); __syncthreads(); }
    }

    float bias[4];
    int   cols[4];
    #pragma unroll
    for (int n = 0; n < 4; ++n) {
        const int c = v0 + wn * 64 + n * 16 + (lane & 15);
        cols[n] = c;
        bias[n] = (c < V) ? b_out[c] : 0.f;
    }
    const int rbase = b0 + wm * 32 + (lane >> 4) * 4;
    #pragma unroll
    for (int i = 0; i < 2; ++i) {
        #pragma unroll
        for (int r = 0; r < 4; ++r) {
            const int row = rbase + i * 16 + r;
            float* dst = logit + (size_t)row * V;
            #pragma unroll
            for (int n = 0; n < 4; ++n) {
                if (cols[n] < V)
                    dst[cols[n]] = tanhf(acc[i][n][r] + bias[n]);
            }
        }
    }
}

// ---------------------------------------------------------------------------
extern "C" void kernel_launch(void* const* d_in, const int* in_sizes, int n_in,
                              void* d_out, int out_size, void* d_ws, size_t ws_size,
                              hipStream_t stream) {
    const int*   input  = (const int*)  d_in[0];
    // d_in[1] = target (unused by forward)
    const float* hidden = (const float*)d_in[2];
    const float* w_ih   = (const float*)d_in[3];
    const float* w_hh   = (const float*)d_in[4];
    const float* b_ih   = (const float*)d_in[5];
    const float* b_hh   = (const float*)d_in[6];
    const float* w_out  = (const float*)d_in[7];
    const float* b_out  = (const float*)d_in[8];

    float* out   = (float*)d_out;
    float* logit = out;                      // first B*V floats
    float* h_new = out + (size_t)B * V;      // then L*B*H floats (L=1)

    const size_t nh = (size_t)B * H;                          // 131,072
    const size_t needed = 2 * nh * sizeof(unsigned short);    // 512 KB

    if (ws_size >= needed) {
        unsigned short* hhi = (unsigned short*)d_ws;
        unsigned short* hlo = hhi + nh;

        gru_cell_v2<<<B / BPB, 256, 0, stream>>>(input, hidden, w_ih, w_hh,
                                                 b_ih, b_hh, h_new, hhi, hlo);
        out_gemm_pipe<<<NVB * NBB, 256, 0, stream>>>(w_out, hhi, hlo,
                                                     b_out, logit);
    } else {
        gru_cell_v2<<<B / BPB, 256, 0, stream>>>(input, hidden, w_ih, w_hh,
                                                 b_ih, b_hh, h_new,
                                                 nullptr, nullptr);
        out_gemm_mfma_reg<<<NVB * NBB, 256, 0, stream>>>(h_new, w_out,
                                                         b_out, logit);
    }
}

// Round 9
// 257.542 us; speedup vs baseline: 1.2900x; 1.2900x over previous
//
#include <hip/hip_runtime.h>
#include <hip/hip_bf16.h>
#include <math.h>

#define V 100000
#define H 256
#define B 512

typedef __bf16 bf16x8 __attribute__((ext_vector_type(8)));
typedef unsigned short u16x8 __attribute__((ext_vector_type(8)));
typedef float  f32x4  __attribute__((ext_vector_type(4)));

__device__ __forceinline__ unsigned short f32_bf16_rne(float x) {
    unsigned u = __float_as_uint(x);
    u += 0x7FFFu + ((u >> 16) & 1u);            // round-to-nearest-even
    return (unsigned short)(u >> 16);
}
__device__ __forceinline__ float bf16u_f32(unsigned short h) {
    return __uint_as_float(((unsigned)h) << 16);
}
__device__ __forceinline__ float fast_tanh(float x) {
    // tanh(x) = 1 - 2/(exp2(2x*log2e)+1); saturates correctly (proven r6)
    float e = __builtin_exp2f(x * 2.8853900817779268f);
    return 1.f - 2.f * __builtin_amdgcn_rcpf(e + 1.f);
}

#define GLOAD_LDS16(g, l)                                                     \
    __builtin_amdgcn_global_load_lds(                                         \
        (const __attribute__((address_space(1))) void*)(g),                   \
        (__attribute__((address_space(3))) void*)(l), 16, 0, 0)

// ---------------------------------------------------------------------------
// Kernel 1 (v3): GRU cell, full-chip grid. 256 blocks = 64 batch-groups (8
// batches) x 4 hidden-quarters (64 j). Fixes v2's 64-block launch (75% of CUs
// idle). Each thread: one j, two batches; w_hh rows read once per block
// (50 MB total). Math identical to the proven v1/v2 path.
// ---------------------------------------------------------------------------
__global__ __launch_bounds__(256) void gru_cell_v3(
    const int*   __restrict__ input,
    const float* __restrict__ hidden,
    const float* __restrict__ w_ih,
    const float* __restrict__ w_hh,
    const float* __restrict__ b_ih,
    const float* __restrict__ b_hh,
    float*       __restrict__ h_out,
    unsigned short* __restrict__ h_hi_p,   // may be null (fallback path)
    unsigned short* __restrict__ h_lo_p)
{
    const int gb  = blockIdx.x >> 2;    // batch group 0..63
    const int q   = blockIdx.x & 3;     // hidden quarter 0..3
    const int b0  = gb * 8;
    const int j0  = q * 64;
    const int tid = threadIdx.x;
    const int jj  = tid & 63;
    const int bq  = tid >> 6;           // wave id -> 2-batch slice
    const int j   = j0 + jj;

    __shared__ float hs[8 * H];         // 8 KB: h for the 8 batches
    __shared__ int   idxs[8];
    #pragma unroll
    for (int i = 0; i < 2; ++i) {
        const int p = i * 256 + tid;    // 512 float4s total
        reinterpret_cast<float4*>(hs)[p] =
            reinterpret_cast<const float4*>(hidden + (size_t)b0 * H)[p];
    }
    if (tid < 8) idxs[tid] = input[b0 + tid];
    __syncthreads();

    const int ba = bq * 2, bb = bq * 2 + 1;
    const int ia = idxs[ba], ib = idxs[bb];

    // scattered gathers issued early; latency hides under the w_hh loop
    const float g_ra = w_ih[(size_t) j          * V + ia];
    const float g_rb = w_ih[(size_t) j          * V + ib];
    const float g_za = w_ih[(size_t)(j +     H) * V + ia];
    const float g_zb = w_ih[(size_t)(j +     H) * V + ib];
    const float g_na = w_ih[(size_t)(j + 2 * H) * V + ia];
    const float g_nb = w_ih[(size_t)(j + 2 * H) * V + ib];

    const float4* wr = reinterpret_cast<const float4*>(&w_hh[(size_t) j          * H]);
    const float4* wz = reinterpret_cast<const float4*>(&w_hh[(size_t)(j +     H) * H]);
    const float4* wn = reinterpret_cast<const float4*>(&w_hh[(size_t)(j + 2 * H) * H]);
    const float4* ha = reinterpret_cast<const float4*>(&hs[ba * H]);
    const float4* hb = reinterpret_cast<const float4*>(&hs[bb * H]);

    float ara = 0.f, aza = 0.f, ana = 0.f;
    float arb = 0.f, azb = 0.f, anb = 0.f;
    #pragma unroll 4
    for (int k = 0; k < H / 4; ++k) {
        const float4 a = wr[k];
        const float4 c = wz[k];
        const float4 d = wn[k];
        const float4 va = ha[k];    // wave-uniform LDS address -> broadcast
        const float4 vb = hb[k];
        ara += a.x * va.x + a.y * va.y + a.z * va.z + a.w * va.w;
        aza += c.x * va.x + c.y * va.y + c.z * va.z + c.w * va.w;
        ana += d.x * va.x + d.y * va.y + d.z * va.z + d.w * va.w;
        arb += a.x * vb.x + a.y * vb.y + a.z * vb.z + a.w * vb.w;
        azb += c.x * vb.x + c.y * vb.y + c.z * vb.z + c.w * vb.w;
        anb += d.x * vb.x + d.y * vb.y + d.z * vb.z + d.w * vb.w;
    }

    const float bir = b_ih[j], biz = b_ih[j + H], bin = b_ih[j + 2 * H];
    const float bhr = b_hh[j], bhz = b_hh[j + H], bhn = b_hh[j + 2 * H];

    #pragma unroll
    for (int s = 0; s < 2; ++s) {
        const float gi_r = (s ? g_rb : g_ra) + bir;
        const float gi_z = (s ? g_zb : g_za) + biz;
        const float gi_n = (s ? g_nb : g_na) + bin;
        const float h_r  = (s ? arb : ara) + bhr;
        const float h_z  = (s ? azb : aza) + bhz;
        const float h_n  = (s ? anb : ana) + bhn;
        const int   bg   = b0 + (s ? bb : ba);

        const float r = 1.f / (1.f + expf(-(gi_r + h_r)));
        const float z = 1.f / (1.f + expf(-(gi_z + h_z)));
        const float n = tanhf(gi_n + r * h_n);
        const float hprev = hs[(s ? bb : ba) * H + jj + j0];
        const float val = (1.f - z) * n + z * hprev;

        h_out[(size_t)bg * H + j] = val;
        if (h_hi_p != nullptr) {
            const unsigned short hh = f32_bf16_rne(val);
            h_hi_p[(size_t)bg * H + j] = hh;
            h_lo_p[(size_t)bg * H + j] = f32_bf16_rne(val - bf16u_f32(hh));
        }
    }
}

// ---------------------------------------------------------------------------
// Kernel 2 (barrier-free): logit = tanh(h_new @ w_out.T + b_out).
// Both MFMA operands are K-major with K contiguous in memory, so:
//  - B (w_out fp32) fragments load STRAIGHT from global per-lane (16 rows x
//    64B per instr), hi/lo-split in registers, prefetched one k-step ahead.
//    No w LDS, no barriers, no phase-locking.
//  - A (h planes) staged ONCE per block into 64 KB XOR-swizzled LDS (proven
//    gload_lds path), one __syncthreads() total.
// Block = 64 batch x 256 vocab, 4 waves (one 64x64 tile each), acc[4][4].
// Grid 391x8 = 3128 with bijective XCD swizzle (8 x 391 exact).
// Fragment layout / rounding / epilogue identical to the verified r4-r8 path.
// ---------------------------------------------------------------------------
#define DBM  64
#define DBN  256
#define NVB3 391   // ceil(V/DBN)

__global__ __launch_bounds__(256, 2) void out_gemm_direct(
    const float*          __restrict__ w_out,  // (V,H) fp32
    const unsigned short* __restrict__ hhi_g,  // (B,H) bf16 hi plane
    const unsigned short* __restrict__ hlo_g,  // (B,H) bf16 lo plane
    const float*          __restrict__ b_out,  // (V)
    float*                __restrict__ logit)  // (B,V)
{
    __shared__ unsigned short h_hi_s[DBM * H];   // 32 KB
    __shared__ unsigned short h_lo_s[DBM * H];   // 32 KB

    const int tid  = threadIdx.x;
    const int lane = tid & 63;
    const int wid  = tid >> 6;

    // bijective XCD-chunked swizzle; batch-block fastest so the 8 blocks
    // sharing a w tile run consecutively on the same XCD (L2 reuse).
    const int bid = blockIdx.x;                    // 0..3127
    const int wg  = (bid & 7) * NVB3 + (bid >> 3);
    const int vb  = wg >> 3;                       // vocab block 0..390
    const int bx  = wg & 7;                        // batch block 0..7
    const int b0  = bx * DBM;
    const int v0  = vb * DBN;
    const int vw  = v0 + wid * 64;                 // this wave's vocab base

    // ---- stage h planes once: linear LDS dest + inverse-swizzled source ----
    #pragma unroll
    for (int i = 0; i < 8; ++i) {
        const int pbase = i * 4096 + (wid << 10);      // wave-uniform dest
        const int p     = pbase + (lane << 4);         // per-lane linear byte
        const int row   = p >> 9;                      // 512 B per row (256 k)
        const int kb    = p & 511;
        const int swz   = kb ^ ((row & 7) << 4);
        const size_t gb = (size_t)(b0 + row) * 512 + swz;
        GLOAD_LDS16((const char*)hhi_g + gb, (char*)h_hi_s + pbase);
        GLOAD_LDS16((const char*)hlo_g + gb, (char*)h_lo_s + pbase);
    }
    __syncthreads();   // the ONLY barrier; includes vmcnt drain of the stage

    f32x4 acc[4][4];
    #pragma unroll
    for (int m = 0; m < 4; ++m)
        #pragma unroll
        for (int n = 0; n < 4; ++n)
            acc[m][n] = f32x4{0.f, 0.f, 0.f, 0.f};

    auto loadW = [&](float4* wreg, int t) {
        #pragma unroll
        for (int n = 0; n < 4; ++n) {
            int v = vw + n * 16 + (lane & 15);
            if (v > V - 1) v = V - 1;                  // clamp; masked at store
            const size_t bo = (size_t)v * 1024 + t * 128 + ((lane >> 4) << 5);
            wreg[n * 2]     = *reinterpret_cast<const float4*>(
                                  reinterpret_cast<const char*>(w_out) + bo);
            wreg[n * 2 + 1] = *reinterpret_cast<const float4*>(
                                  reinterpret_cast<const char*>(w_out) + bo + 16);
        }
    };

    auto step = [&](int t, const float4* wreg) {
        // A fragments from swizzled LDS (conflict-free, proven pattern)
        const int kbyte = t * 64 + ((lane >> 4) << 4);
        bf16x8 ah[4], al[4];
        #pragma unroll
        for (int m = 0; m < 4; ++m) {
            const int row = m * 16 + (lane & 15);
            const int off = row * 512 + (kbyte ^ ((row & 7) << 4));
            ah[m] = *reinterpret_cast<const bf16x8*>(
                        reinterpret_cast<const char*>(h_hi_s) + off);
            al[m] = *reinterpret_cast<const bf16x8*>(
                        reinterpret_cast<const char*>(h_lo_s) + off);
        }
        // B fragments: in-register hi/lo split of the prefetched fp32 w
        bf16x8 bh[4], bl[4];
        #pragma unroll
        for (int n = 0; n < 4; ++n) {
            const float4 fa = wreg[n * 2];
            const float4 fb = wreg[n * 2 + 1];
            const float f[8] = {fa.x, fa.y, fa.z, fa.w, fb.x, fb.y, fb.z, fb.w};
            u16x8 uh, ul;
            #pragma unroll
            for (int e = 0; e < 8; ++e) {
                const unsigned short hv = f32_bf16_rne(f[e]);
                uh[e] = hv;
                ul[e] = f32_bf16_rne(f[e] - bf16u_f32(hv));
            }
            bh[n] = __builtin_bit_cast(bf16x8, uh);
            bl[n] = __builtin_bit_cast(bf16x8, ul);
        }
        #pragma unroll
        for (int n = 0; n < 4; ++n) {
            #pragma unroll
            for (int m = 0; m < 4; ++m) {
                acc[m][n] = __builtin_amdgcn_mfma_f32_16x16x32_bf16(ah[m], bh[n], acc[m][n], 0, 0, 0);
                acc[m][n] = __builtin_amdgcn_mfma_f32_16x16x32_bf16(ah[m], bl[n], acc[m][n], 0, 0, 0);
                acc[m][n] = __builtin_amdgcn_mfma_f32_16x16x32_bf16(al[m], bh[n], acc[m][n], 0, 0, 0);
            }
        }
    };

    // K = 256 -> 8 k-steps of 32; w prefetched one step ahead, fully unrolled
    float4 wA[8], wB[8];
    loadW(wA, 0);
    #pragma unroll
    for (int tt = 0; tt < 4; ++tt) {
        loadW(wB, tt * 2 + 1);      // issue next k-step's loads
        step(tt * 2, wA);           // consume current (vmcnt-counted wait)
        if (tt < 3) loadW(wA, tt * 2 + 2);
        step(tt * 2 + 1, wB);
    }

    // Epilogue: bias + tanh + masked store. C/D: col=lane&15, row=(lane>>4)*4+r.
    float bias[4];
    int   cols[4];
    #pragma unroll
    for (int n = 0; n < 4; ++n) {
        const int c = vw + n * 16 + (lane & 15);
        cols[n] = c;
        bias[n] = (c < V) ? b_out[c] : 0.f;
    }
    const int rbase = b0 + ((lane >> 4) << 2);
    #pragma unroll
    for (int m = 0; m < 4; ++m) {
        #pragma unroll
        for (int r = 0; r < 4; ++r) {
            const int row = rbase + m * 16 + r;
            float* dst = logit + (size_t)row * V;
            #pragma unroll
            for (int n = 0; n < 4; ++n) {
                if (cols[n] < V)
                    dst[cols[n]] = fast_tanh(acc[m][n][r] + bias[n]);
            }
        }
    }
}

// ---------------------------------------------------------------------------
// Fallback kernel (round-4, proven): reg-staged split-bf16 GEMM, used only if
// ws_size can't hold the h planes.
// ---------------------------------------------------------------------------
#define BM  64
#define BN  128
#define BK  64
#define NVB 782   // ceil(V/BN)
#define NBB 8     // B/BM

__global__ __launch_bounds__(256) void out_gemm_mfma_reg(
    const float* __restrict__ hnew,
    const float* __restrict__ w_out,
    const float* __restrict__ b_out,
    float*       __restrict__ logit)
{
    __shared__ unsigned short w_hi[BN * BK];
    __shared__ unsigned short w_lo[BN * BK];
    __shared__ unsigned short h_hi[BM * BK];
    __shared__ unsigned short h_lo[BM * BK];

    const int tid  = threadIdx.x;
    const int lane = tid & 63;
    const int wid  = tid >> 6;
    const int wm   = wid >> 1;
    const int wn   = wid & 1;

    const int bid = blockIdx.x;
    const int wg  = (bid & 7) * NVB + (bid >> 3);
    const int bx  = wg & 7;
    const int by  = wg >> 3;
    const int b0  = bx * BM;
    const int v0  = by * BN;

    float4 wreg[8];
    float4 hreg[4];

    auto load_chunk = [&](int k0) {
        #pragma unroll
        for (int i = 0; i < 8; ++i) {
            const int idx4 = i * 256 + tid;
            const int row  = idx4 >> 4;
            const int k4   = (idx4 & 15) << 2;
            int vg = v0 + row; if (vg > V - 1) vg = V - 1;
            wreg[i] = *reinterpret_cast<const float4*>(&w_out[(size_t)vg * H + k0 + k4]);
        }
        #pragma unroll
        for (int i = 0; i < 4; ++i) {
            const int idx4 = i * 256 + tid;
            const int row  = idx4 >> 4;
            const int k4   = (idx4 & 15) << 2;
            hreg[i] = *reinterpret_cast<const float4*>(&hnew[(b0 + row) * H + k0 + k4]);
        }
    };

    auto store_chunk = [&]() {
        #pragma unroll
        for (int i = 0; i < 8; ++i) {
            const int idx4 = i * 256 + tid;
            const int row  = idx4 >> 4;
            const int k4   = (idx4 & 15) << 2;
            const int off  = row * (BK * 2) + ((k4 * 2) ^ ((row & 7) << 4));
            const float f[4] = {wreg[i].x, wreg[i].y, wreg[i].z, wreg[i].w};
            unsigned short hv[4], lv[4];
            #pragma unroll
            for (int jj = 0; jj < 4; ++jj) {
                hv[jj] = f32_bf16_rne(f[jj]);
                lv[jj] = f32_bf16_rne(f[jj] - bf16u_f32(hv[jj]));
            }
            *reinterpret_cast<ushort4*>(reinterpret_cast<char*>(w_hi) + off) =
                make_ushort4(hv[0], hv[1], hv[2], hv[3]);
            *reinterpret_cast<ushort4*>(reinterpret_cast<char*>(w_lo) + off) =
                make_ushort4(lv[0], lv[1], lv[2], lv[3]);
        }
        #pragma unroll
        for (int i = 0; i < 4; ++i) {
            const int idx4 = i * 256 + tid;
            const int row  = idx4 >> 4;
            const int k4   = (idx4 & 15) << 2;
            const int off  = row * (BK * 2) + ((k4 * 2) ^ ((row & 7) << 4));
            const float f[4] = {hreg[i].x, hreg[i].y, hreg[i].z, hreg[i].w};
            unsigned short hv[4], lv[4];
            #pragma unroll
            for (int jj = 0; jj < 4; ++jj) {
                hv[jj] = f32_bf16_rne(f[jj]);
                lv[jj] = f32_bf16_rne(f[jj] - bf16u_f32(hv[jj]));
            }
            *reinterpret_cast<ushort4*>(reinterpret_cast<char*>(h_hi) + off) =
                make_ushort4(hv[0], hv[1], hv[2], hv[3]);
            *reinterpret_cast<ushort4*>(reinterpret_cast<char*>(h_lo) + off) =
                make_ushort4(lv[0], lv[1], lv[2], lv[3]);
        }
    };

    f32x4 acc[2][4];
    #pragma unroll
    for (int i = 0; i < 2; ++i)
        #pragma unroll
        for (int n = 0; n < 4; ++n)
            acc[i][n] = f32x4{0.f, 0.f, 0.f, 0.f};

    auto compute = [&]() {
        #pragma unroll
        for (int ks = 0; ks < 2; ++ks) {
            const int kb = ks * 64 + (lane >> 4) * 16;
            bf16x8 ah[2], al[2];
            #pragma unroll
            for (int i = 0; i < 2; ++i) {
                const int row = wm * 32 + i * 16 + (lane & 15);
                const int off = row * (BK * 2) + (kb ^ ((row & 7) << 4));
                ah[i] = *reinterpret_cast<const bf16x8*>(
                            reinterpret_cast<const char*>(h_hi) + off);
                al[i] = *reinterpret_cast<const bf16x8*>(
                            reinterpret_cast<const char*>(h_lo) + off);
            }
            #pragma unroll
            for (int n = 0; n < 4; ++n) {
                const int row = wn * 64 + n * 16 + (lane & 15);
                const int off = row * (BK * 2) + (kb ^ ((row & 7) << 4));
                const bf16x8 bh = *reinterpret_cast<const bf16x8*>(
                            reinterpret_cast<const char*>(w_hi) + off);
                const bf16x8 bl = *reinterpret_cast<const bf16x8*>(
                            reinterpret_cast<const char*>(w_lo) + off);
                #pragma unroll
                for (int i = 0; i < 2; ++i) {
                    acc[i][n] = __builtin_amdgcn_mfma_f32_16x16x32_bf16(ah[i], bh, acc[i][n], 0, 0, 0);
                    acc[i][n] = __builtin_amdgcn_mfma_f32_16x16x32_bf16(ah[i], bl, acc[i][n], 0, 0, 0);
                    acc[i][n] = __builtin_amdgcn_mfma_f32_16x16x32_bf16(al[i], bh, acc[i][n], 0, 0, 0);
                }
            }
        }
    };

    load_chunk(0);
    store_chunk();
    __syncthreads();
    for (int t = 0; t < 4; ++t) {
        if (t < 3) load_chunk((t + 1) * BK);
        compute();
        __syncthreads();
        if (t < 3) { store_chunk(); __syncthreads(); }
    }

    float bias[4];
    int   cols[4];
    #pragma unroll
    for (int n = 0; n < 4; ++n) {
        const int c = v0 + wn * 64 + n * 16 + (lane & 15);
        cols[n] = c;
        bias[n] = (c < V) ? b_out[c] : 0.f;
    }
    const int rbase = b0 + wm * 32 + (lane >> 4) * 4;
    #pragma unroll
    for (int i = 0; i < 2; ++i) {
        #pragma unroll
        for (int r = 0; r < 4; ++r) {
            const int row = rbase + i * 16 + r;
            float* dst = logit + (size_t)row * V;
            #pragma unroll
            for (int n = 0; n < 4; ++n) {
                if (cols[n] < V)
                    dst[cols[n]] = tanhf(acc[i][n][r] + bias[n]);
            }
        }
    }
}

// ---------------------------------------------------------------------------
extern "C" void kernel_launch(void* const* d_in, const int* in_sizes, int n_in,
                              void* d_out, int out_size, void* d_ws, size_t ws_size,
                              hipStream_t stream) {
    const int*   input  = (const int*)  d_in[0];
    // d_in[1] = target (unused by forward)
    const float* hidden = (const float*)d_in[2];
    const float* w_ih   = (const float*)d_in[3];
    const float* w_hh   = (const float*)d_in[4];
    const float* b_ih   = (const float*)d_in[5];
    const float* b_hh   = (const float*)d_in[6];
    const float* w_out  = (const float*)d_in[7];
    const float* b_out  = (const float*)d_in[8];

    float* out   = (float*)d_out;
    float* logit = out;                      // first B*V floats
    float* h_new = out + (size_t)B * V;      // then L*B*H floats (L=1)

    const size_t nh = (size_t)B * H;                          // 131,072
    const size_t needed = 2 * nh * sizeof(unsigned short);    // 512 KB

    if (ws_size >= needed) {
        unsigned short* hhi = (unsigned short*)d_ws;
        unsigned short* hlo = hhi + nh;

        gru_cell_v3<<<256, 256, 0, stream>>>(input, hidden, w_ih, w_hh,
                                             b_ih, b_hh, h_new, hhi, hlo);
        out_gemm_direct<<<NVB3 * 8, 256, 0, stream>>>(w_out, hhi, hlo,
                                                      b_out, logit);
    } else {
        gru_cell_v3<<<256, 256, 0, stream>>>(input, hidden, w_ih, w_hh,
                                             b_ih, b_hh, h_new,
                                             nullptr, nullptr);
        out_gemm_mfma_reg<<<NVB * NBB, 256, 0, stream>>>(h_new, w_out,
                                                         b_out, logit);
    }
}

// Round 10
// 239.542 us; speedup vs baseline: 1.3869x; 1.0751x over previous
//
#include <hip/hip_runtime.h>
#include <hip/hip_bf16.h>
#include <math.h>

#define V 100000
#define H 256
#define B 512

typedef __bf16 bf16x8 __attribute__((ext_vector_type(8)));
typedef float  f32x4  __attribute__((ext_vector_type(4)));

__device__ __forceinline__ unsigned short f32_bf16_rne(float x) {
    unsigned u = __float_as_uint(x);
    u += 0x7FFFu + ((u >> 16) & 1u);            // round-to-nearest-even
    return (unsigned short)(u >> 16);
}
__device__ __forceinline__ float bf16u_f32(unsigned short h) {
    return __uint_as_float(((unsigned)h) << 16);
}
__device__ __forceinline__ float fast_tanh(float x) {
    // tanh(x) = 1 - 2/(exp2(2x*log2e)+1); saturates correctly (proven r6)
    float e = __builtin_exp2f(x * 2.8853900817779268f);
    return 1.f - 2.f * __builtin_amdgcn_rcpf(e + 1.f);
}

#define GLOAD_LDS16(g, l)                                                     \
    __builtin_amdgcn_global_load_lds(                                         \
        (const __attribute__((address_space(1))) void*)(g),                   \
        (__attribute__((address_space(3))) void*)(l), 16, 0, 0)

// ---------------------------------------------------------------------------
// Kernel 1 (fused): blocks 0..255 run the GRU cell (v3 layout, proven R9);
// blocks 256..2303 split w_out fp32 -> bf16 hi/lo planes (proven R6).
// The two halves are independent; fusing overlaps them (saves ~20 us of
// serial launch time vs two kernels).
// ---------------------------------------------------------------------------
#define PREP_GRID 2304   // 256 gru blocks + 2048 split blocks

__global__ __launch_bounds__(256) void gru_and_split(
    const int*   __restrict__ input,
    const float* __restrict__ hidden,
    const float* __restrict__ w_ih,
    const float* __restrict__ w_hh,
    const float* __restrict__ b_ih,
    const float* __restrict__ b_hh,
    const float* __restrict__ w_out,
    float*       __restrict__ h_out,
    unsigned short* __restrict__ h_hi_p,
    unsigned short* __restrict__ h_lo_p,
    unsigned short* __restrict__ w_hi_p,
    unsigned short* __restrict__ w_lo_p)
{
    if (blockIdx.x >= 256) {
        // ---- split w_out into bf16 hi/lo planes (grid-stride, streaming) ----
        const int total4 = (V * H) / 4;   // 6,400,000 float4s
        for (int i = (blockIdx.x - 256) * 256 + threadIdx.x; i < total4;
             i += 2048 * 256) {
            const float4 x = reinterpret_cast<const float4*>(w_out)[i];
            const float f[4] = {x.x, x.y, x.z, x.w};
            ushort4 hv, lv;
            unsigned short* hp = &hv.x;
            unsigned short* lp = &lv.x;
            #pragma unroll
            for (int jj = 0; jj < 4; ++jj) {
                hp[jj] = f32_bf16_rne(f[jj]);
                lp[jj] = f32_bf16_rne(f[jj] - bf16u_f32(hp[jj]));
            }
            reinterpret_cast<ushort4*>(w_hi_p)[i] = hv;
            reinterpret_cast<ushort4*>(w_lo_p)[i] = lv;
        }
        return;
    }

    // ---- GRU cell: 64 batch-groups x 4 hidden-quarters (v3, proven R9) ----
    const int gb  = blockIdx.x >> 2;    // batch group 0..63
    const int q   = blockIdx.x & 3;     // hidden quarter 0..3
    const int b0  = gb * 8;
    const int j0  = q * 64;
    const int tid = threadIdx.x;
    const int jj  = tid & 63;
    const int bq  = tid >> 6;           // wave id -> 2-batch slice
    const int j   = j0 + jj;

    __shared__ float hs[8 * H];         // 8 KB
    __shared__ int   idxs[8];
    #pragma unroll
    for (int i = 0; i < 2; ++i) {
        const int p = i * 256 + tid;    // 512 float4s total
        reinterpret_cast<float4*>(hs)[p] =
            reinterpret_cast<const float4*>(hidden + (size_t)b0 * H)[p];
    }
    if (tid < 8) idxs[tid] = input[b0 + tid];
    __syncthreads();

    const int ba = bq * 2, bb = bq * 2 + 1;
    const int ia = idxs[ba], ib = idxs[bb];

    const float g_ra = w_ih[(size_t) j          * V + ia];
    const float g_rb = w_ih[(size_t) j          * V + ib];
    const float g_za = w_ih[(size_t)(j +     H) * V + ia];
    const float g_zb = w_ih[(size_t)(j +     H) * V + ib];
    const float g_na = w_ih[(size_t)(j + 2 * H) * V + ia];
    const float g_nb = w_ih[(size_t)(j + 2 * H) * V + ib];

    const float4* wr = reinterpret_cast<const float4*>(&w_hh[(size_t) j          * H]);
    const float4* wz = reinterpret_cast<const float4*>(&w_hh[(size_t)(j +     H) * H]);
    const float4* wn = reinterpret_cast<const float4*>(&w_hh[(size_t)(j + 2 * H) * H]);
    const float4* ha = reinterpret_cast<const float4*>(&hs[ba * H]);
    const float4* hb = reinterpret_cast<const float4*>(&hs[bb * H]);

    float ara = 0.f, aza = 0.f, ana = 0.f;
    float arb = 0.f, azb = 0.f, anb = 0.f;
    #pragma unroll 4
    for (int k = 0; k < H / 4; ++k) {
        const float4 a = wr[k];
        const float4 c = wz[k];
        const float4 d = wn[k];
        const float4 va = ha[k];
        const float4 vb = hb[k];
        ara += a.x * va.x + a.y * va.y + a.z * va.z + a.w * va.w;
        aza += c.x * va.x + c.y * va.y + c.z * va.z + c.w * va.w;
        ana += d.x * va.x + d.y * va.y + d.z * va.z + d.w * va.w;
        arb += a.x * vb.x + a.y * vb.y + a.z * vb.z + a.w * vb.w;
        azb += c.x * vb.x + c.y * vb.y + c.z * vb.z + c.w * vb.w;
        anb += d.x * vb.x + d.y * vb.y + d.z * vb.z + d.w * vb.w;
    }

    const float bir = b_ih[j], biz = b_ih[j + H], bin = b_ih[j + 2 * H];
    const float bhr = b_hh[j], bhz = b_hh[j + H], bhn = b_hh[j + 2 * H];

    #pragma unroll
    for (int s = 0; s < 2; ++s) {
        const float gi_r = (s ? g_rb : g_ra) + bir;
        const float gi_z = (s ? g_zb : g_za) + biz;
        const float gi_n = (s ? g_nb : g_na) + bin;
        const float h_r  = (s ? arb : ara) + bhr;
        const float h_z  = (s ? azb : aza) + bhz;
        const float h_n  = (s ? anb : ana) + bhn;
        const int   bg   = b0 + (s ? bb : ba);

        const float r = 1.f / (1.f + expf(-(gi_r + h_r)));
        const float z = 1.f / (1.f + expf(-(gi_z + h_z)));
        const float n = tanhf(gi_n + r * h_n);
        const float hprev = hs[(s ? bb : ba) * H + jj + j0];
        const float val = (1.f - z) * n + z * hprev;

        h_out[(size_t)bg * H + j] = val;
        if (h_hi_p != nullptr) {
            const unsigned short hh = f32_bf16_rne(val);
            h_hi_p[(size_t)bg * H + j] = hh;
            h_lo_p[(size_t)bg * H + j] = f32_bf16_rne(val - bf16u_f32(hh));
        }
    }
}

// ---------------------------------------------------------------------------
// Kernel 2 (lean): logit = tanh(h_new @ w_out.T + b_out), split-bf16 MFMA.
// EXACT R6 structure (175 us, refchecked) with ONE change: h A-fragments come
// from per-lane register loads of the pre-split h planes (L2-hot, issued with
// the stage and drained by the same barrier; addressing proven in R9) instead
// of LDS. LDS drops 48->32 KB => 5 blocks/CU (was 3), occupancy ~28%->~60%.
// Every latency event (stage drain, L2 miss) is now covered by 4 other
// resident blocks. Fragment math / swizzle / epilogue byte-identical.
// ---------------------------------------------------------------------------
#define BM  64
#define BN  128
#define BK  64
#define NVB 782   // ceil(V/BN)
#define NBB 8     // B/BM

__global__ __launch_bounds__(256, 4) void out_gemm_lean(
    const unsigned short* __restrict__ whi_g,  // (V,H) bf16 hi plane
    const unsigned short* __restrict__ wlo_g,  // (V,H) bf16 lo plane
    const unsigned short* __restrict__ hhi_g,  // (B,H) bf16 hi plane
    const unsigned short* __restrict__ hlo_g,  // (B,H) bf16 lo plane
    const float*          __restrict__ b_out,  // (V)
    float*                __restrict__ logit)  // (B,V)
{
    __shared__ unsigned short w_hi_s[BN * BK];   // 16 KB
    __shared__ unsigned short w_lo_s[BN * BK];   // 16 KB  -> 32 KB total

    const int tid  = threadIdx.x;
    const int lane = tid & 63;
    const int wid  = tid >> 6;
    const int wm   = wid >> 1;      // batch half (0..1)
    const int wn   = wid & 1;       // vocab half (0..1)

    // bijective XCD-chunked swizzle, batch-fastest (proven: FETCH ~53 MB)
    const int bid = blockIdx.x;                    // 0..6255
    const int wg  = (bid & 7) * NVB + (bid >> 3);
    const int bx  = wg & 7;                        // batch block
    const int by  = wg >> 3;                       // vocab block
    const int b0  = bx * BM;
    const int v0  = by * BN;

    // ---- w staging: 8 global_load_lds, pre-swizzled source (R6 proven) ----
    auto stage = [&](int k0) {
        #pragma unroll
        for (int i = 0; i < 4; ++i) {
            const int p    = i * 4096 + (wid << 10) + (lane << 4);
            const int row  = p >> 7;               // local vocab row 0..127
            const int lb   = p & 127;
            const int swz  = lb ^ ((row & 7) << 4);
            int vg = v0 + row; if (vg > V - 1) vg = V - 1;
            const size_t gb = (size_t)vg * (H * 2) + (size_t)(k0 * 2) + swz;
            const int dst  = i * 4096 + (wid << 10);
            GLOAD_LDS16((const char*)whi_g + gb, (char*)w_hi_s + dst);
            GLOAD_LDS16((const char*)wlo_g + gb, (char*)w_lo_s + dst);
        }
    };

    // ---- h A-fragments: per-lane direct loads from bf16 planes (R9 proven) --
    bf16x8 ah[4], al[4];   // [i*2+ks]
    auto loadA = [&](int t) {
        #pragma unroll
        for (int i = 0; i < 2; ++i) {
            #pragma unroll
            for (int ks = 0; ks < 2; ++ks) {
                const size_t ho = ((size_t)(b0 + wm * 32 + i * 16 + (lane & 15)) * H
                                   + t * BK + ks * 32 + (lane >> 4) * 8) * 2;
                ah[i * 2 + ks] = *reinterpret_cast<const bf16x8*>(
                                     reinterpret_cast<const char*>(hhi_g) + ho);
                al[i * 2 + ks] = *reinterpret_cast<const bf16x8*>(
                                     reinterpret_cast<const char*>(hlo_g) + ho);
            }
        }
    };

    f32x4 acc[2][4];
    #pragma unroll
    for (int i = 0; i < 2; ++i)
        #pragma unroll
        for (int n = 0; n < 4; ++n)
            acc[i][n] = f32x4{0.f, 0.f, 0.f, 0.f};

    auto compute = [&]() {
        #pragma unroll
        for (int ks = 0; ks < 2; ++ks) {
            const int kb = ks * 64 + (lane >> 4) * 16;   // LDS k byte offset
            bf16x8 bh[4], bl[4];
            #pragma unroll
            for (int n = 0; n < 4; ++n) {
                const int row = wn * 64 + n * 16 + (lane & 15);
                const int off = row * (BK * 2) + (kb ^ ((row & 7) << 4));
                bh[n] = *reinterpret_cast<const bf16x8*>(
                            reinterpret_cast<const char*>(w_hi_s) + off);
                bl[n] = *reinterpret_cast<const bf16x8*>(
                            reinterpret_cast<const char*>(w_lo_s) + off);
            }
            #pragma unroll
            for (int n = 0; n < 4; ++n) {
                #pragma unroll
                for (int i = 0; i < 2; ++i) {
                    const bf16x8 a_h = ah[i * 2 + ks];
                    const bf16x8 a_l = al[i * 2 + ks];
                    acc[i][n] = __builtin_amdgcn_mfma_f32_16x16x32_bf16(a_h, bh[n], acc[i][n], 0, 0, 0);
                    acc[i][n] = __builtin_amdgcn_mfma_f32_16x16x32_bf16(a_h, bl[n], acc[i][n], 0, 0, 0);
                    acc[i][n] = __builtin_amdgcn_mfma_f32_16x16x32_bf16(a_l, bh[n], acc[i][n], 0, 0, 0);
                }
            }
        }
    };

    // R6's proven 2-barrier drain loop; drain covered by 5 resident blocks/CU.
    #pragma unroll
    for (int t = 0; t < 4; ++t) {
        stage(t * BK);
        loadA(t);
        __syncthreads();            // vmcnt drain + barrier: LDS + A regs ready
        compute();
        __syncthreads();            // reads done before next stage overwrites
    }

    // Epilogue: bias + tanh + masked store. C/D: col=lane&15, row=(lane>>4)*4+r.
    float bias[4];
    int   cols[4];
    #pragma unroll
    for (int n = 0; n < 4; ++n) {
        const int c = v0 + wn * 64 + n * 16 + (lane & 15);
        cols[n] = c;
        bias[n] = (c < V) ? b_out[c] : 0.f;
    }
    const int rbase = b0 + wm * 32 + (lane >> 4) * 4;
    #pragma unroll
    for (int i = 0; i < 2; ++i) {
        #pragma unroll
        for (int r = 0; r < 4; ++r) {
            const int row = rbase + i * 16 + r;
            float* dst = logit + (size_t)row * V;
            #pragma unroll
            for (int n = 0; n < 4; ++n) {
                if (cols[n] < V)
                    dst[cols[n]] = fast_tanh(acc[i][n][r] + bias[n]);
            }
        }
    }
}

// ---------------------------------------------------------------------------
// Fallback kernel (round-4, proven): reg-staged split-bf16 GEMM, used only if
// ws_size can't hold the planes.
// ---------------------------------------------------------------------------
__global__ __launch_bounds__(256) void out_gemm_mfma_reg(
    const float* __restrict__ hnew,
    const float* __restrict__ w_out,
    const float* __restrict__ b_out,
    float*       __restrict__ logit)
{
    __shared__ unsigned short w_hi[BN * BK];
    __shared__ unsigned short w_lo[BN * BK];
    __shared__ unsigned short h_hi[BM * BK];
    __shared__ unsigned short h_lo[BM * BK];

    const int tid  = threadIdx.x;
    const int lane = tid & 63;
    const int wid  = tid >> 6;
    const int wm   = wid >> 1;
    const int wn   = wid & 1;

    const int bid = blockIdx.x;
    const int wg  = (bid & 7) * NVB + (bid >> 3);
    const int bx  = wg & 7;
    const int by  = wg >> 3;
    const int b0  = bx * BM;
    const int v0  = by * BN;

    float4 wreg[8];
    float4 hreg[4];

    auto load_chunk = [&](int k0) {
        #pragma unroll
        for (int i = 0; i < 8; ++i) {
            const int idx4 = i * 256 + tid;
            const int row  = idx4 >> 4;
            const int k4   = (idx4 & 15) << 2;
            int vg = v0 + row; if (vg > V - 1) vg = V - 1;
            wreg[i] = *reinterpret_cast<const float4*>(&w_out[(size_t)vg * H + k0 + k4]);
        }
        #pragma unroll
        for (int i = 0; i < 4; ++i) {
            const int idx4 = i * 256 + tid;
            const int row  = idx4 >> 4;
            const int k4   = (idx4 & 15) << 2;
            hreg[i] = *reinterpret_cast<const float4*>(&hnew[(b0 + row) * H + k0 + k4]);
        }
    };

    auto store_chunk = [&]() {
        #pragma unroll
        for (int i = 0; i < 8; ++i) {
            const int idx4 = i * 256 + tid;
            const int row  = idx4 >> 4;
            const int k4   = (idx4 & 15) << 2;
            const int off  = row * (BK * 2) + ((k4 * 2) ^ ((row & 7) << 4));
            const float f[4] = {wreg[i].x, wreg[i].y, wreg[i].z, wreg[i].w};
            unsigned short hv[4], lv[4];
            #pragma unroll
            for (int jj = 0; jj < 4; ++jj) {
                hv[jj] = f32_bf16_rne(f[jj]);
                lv[jj] = f32_bf16_rne(f[jj] - bf16u_f32(hv[jj]));
            }
            *reinterpret_cast<ushort4*>(reinterpret_cast<char*>(w_hi) + off) =
                make_ushort4(hv[0], hv[1], hv[2], hv[3]);
            *reinterpret_cast<ushort4*>(reinterpret_cast<char*>(w_lo) + off) =
                make_ushort4(lv[0], lv[1], lv[2], lv[3]);
        }
        #pragma unroll
        for (int i = 0; i < 4; ++i) {
            const int idx4 = i * 256 + tid;
            const int row  = idx4 >> 4;
            const int k4   = (idx4 & 15) << 2;
            const int off  = row * (BK * 2) + ((k4 * 2) ^ ((row & 7) << 4));
            const float f[4] = {hreg[i].x, hreg[i].y, hreg[i].z, hreg[i].w};
            unsigned short hv[4], lv[4];
            #pragma unroll
            for (int jj = 0; jj < 4; ++jj) {
                hv[jj] = f32_bf16_rne(f[jj]);
                lv[jj] = f32_bf16_rne(f[jj] - bf16u_f32(hv[jj]));
            }
            *reinterpret_cast<ushort4*>(reinterpret_cast<char*>(h_hi) + off) =
                make_ushort4(hv[0], hv[1], hv[2], hv[3]);
            *reinterpret_cast<ushort4*>(reinterpret_cast<char*>(h_lo) + off) =
                make_ushort4(lv[0], lv[1], lv[2], lv[3]);
        }
    };

    f32x4 acc[2][4];
    #pragma unroll
    for (int i = 0; i < 2; ++i)
        #pragma unroll
        for (int n = 0; n < 4; ++n)
            acc[i][n] = f32x4{0.f, 0.f, 0.f, 0.f};

    auto compute = [&]() {
        #pragma unroll
        for (int ks = 0; ks < 2; ++ks) {
            const int kb = ks * 64 + (lane >> 4) * 16;
            bf16x8 ah[2], al[2];
            #pragma unroll
            for (int i = 0; i < 2; ++i) {
                const int row = wm * 32 + i * 16 + (lane & 15);
                const int off = row * (BK * 2) + (kb ^ ((row & 7) << 4));
                ah[i] = *reinterpret_cast<const bf16x8*>(
                            reinterpret_cast<const char*>(h_hi) + off);
                al[i] = *reinterpret_cast<const bf16x8*>(
                            reinterpret_cast<const char*>(h_lo) + off);
            }
            #pragma unroll
            for (int n = 0; n < 4; ++n) {
                const int row = wn * 64 + n * 16 + (lane & 15);
                const int off = row * (BK * 2) + (kb ^ ((row & 7) << 4));
                const bf16x8 bh = *reinterpret_cast<const bf16x8*>(
                            reinterpret_cast<const char*>(w_hi) + off);
                const bf16x8 bl = *reinterpret_cast<const bf16x8*>(
                            reinterpret_cast<const char*>(w_lo) + off);
                #pragma unroll
                for (int i = 0; i < 2; ++i) {
                    acc[i][n] = __builtin_amdgcn_mfma_f32_16x16x32_bf16(ah[i], bh, acc[i][n], 0, 0, 0);
                    acc[i][n] = __builtin_amdgcn_mfma_f32_16x16x32_bf16(ah[i], bl, acc[i][n], 0, 0, 0);
                    acc[i][n] = __builtin_amdgcn_mfma_f32_16x16x32_bf16(al[i], bh, acc[i][n], 0, 0, 0);
                }
            }
        }
    };

    load_chunk(0);
    store_chunk();
    __syncthreads();
    for (int t = 0; t < 4; ++t) {
        if (t < 3) load_chunk((t + 1) * BK);
        compute();
        __syncthreads();
        if (t < 3) { store_chunk(); __syncthreads(); }
    }

    float bias[4];
    int   cols[4];
    #pragma unroll
    for (int n = 0; n < 4; ++n) {
        const int c = v0 + wn * 64 + n * 16 + (lane & 15);
        cols[n] = c;
        bias[n] = (c < V) ? b_out[c] : 0.f;
    }
    const int rbase = b0 + wm * 32 + (lane >> 4) * 4;
    #pragma unroll
    for (int i = 0; i < 2; ++i) {
        #pragma unroll
        for (int r = 0; r < 4; ++r) {
            const int row = rbase + i * 16 + r;
            float* dst = logit + (size_t)row * V;
            #pragma unroll
            for (int n = 0; n < 4; ++n) {
                if (cols[n] < V)
                    dst[cols[n]] = tanhf(acc[i][n][r] + bias[n]);
            }
        }
    }
}

// ---------------------------------------------------------------------------
extern "C" void kernel_launch(void* const* d_in, const int* in_sizes, int n_in,
                              void* d_out, int out_size, void* d_ws, size_t ws_size,
                              hipStream_t stream) {
    const int*   input  = (const int*)  d_in[0];
    // d_in[1] = target (unused by forward)
    const float* hidden = (const float*)d_in[2];
    const float* w_ih   = (const float*)d_in[3];
    const float* w_hh   = (const float*)d_in[4];
    const float* b_ih   = (const float*)d_in[5];
    const float* b_hh   = (const float*)d_in[6];
    const float* w_out  = (const float*)d_in[7];
    const float* b_out  = (const float*)d_in[8];

    float* out   = (float*)d_out;
    float* logit = out;                      // first B*V floats
    float* h_new = out + (size_t)B * V;      // then L*B*H floats (L=1)

    const size_t nw = (size_t)V * H;         // 25,600,000
    const size_t nh = (size_t)B * H;         // 131,072
    const size_t needed = (2 * nw + 2 * nh) * sizeof(unsigned short); // ~103 MB

    if (ws_size >= needed) {
        unsigned short* whi = (unsigned short*)d_ws;
        unsigned short* wlo = whi + nw;
        unsigned short* hhi = wlo + nw;
        unsigned short* hlo = hhi + nh;

        gru_and_split<<<PREP_GRID, 256, 0, stream>>>(
            input, hidden, w_ih, w_hh, b_ih, b_hh, w_out,
            h_new, hhi, hlo, whi, wlo);
        out_gemm_lean<<<NVB * NBB, 256, 0, stream>>>(whi, wlo, hhi, hlo,
                                                     b_out, logit);
    } else {
        // fallback: no workspace -> original proven two-kernel path
        gru_and_split<<<256, 256, 0, stream>>>(
            input, hidden, w_ih, w_hh, b_ih, b_hh, w_out,
            h_new, nullptr, nullptr, nullptr, nullptr);
        out_gemm_mfma_reg<<<NVB * NBB, 256, 0, stream>>>(h_new, w_out,
                                                         b_out, logit);
    }
}